// Round 3
// baseline (27672.696 us; speedup 1.0000x reference)
//
#include <hip/hip_runtime.h>
#include <hip/hip_bf16.h>

#define S_LEN 8192
#define E_DIM 1024
#define H_DIM 2048
#define T_TAGS 50
#define NWG 256            // persistent workgroups for the recurrence
#define RPW (H_DIM / NWG)  // 8 rows per WG

typedef short short8 __attribute__((ext_vector_type(8)));
typedef float floatx4 __attribute__((ext_vector_type(4)));
typedef _Float16 half8 __attribute__((ext_vector_type(8)));
typedef _Float16 half2v __attribute__((ext_vector_type(2)));
typedef unsigned int uint4a __attribute__((ext_vector_type(4)));

__device__ __forceinline__ unsigned short f2bf(float f) {
    unsigned u = __builtin_bit_cast(unsigned, f);
    unsigned r = (u + 0x7fffu + ((u >> 16) & 1u)) >> 16;
    return (unsigned short)r;
}

__device__ __forceinline__ float dot8(half8 a, half8 b, float acc) {
#if __has_builtin(__builtin_amdgcn_fdot2)
    union U { half8 v; half2v p[4]; };
    U ua; ua.v = a; U ub; ub.v = b;
    acc = __builtin_amdgcn_fdot2(ua.p[0], ub.p[0], acc, false);
    acc = __builtin_amdgcn_fdot2(ua.p[1], ub.p[1], acc, false);
    acc = __builtin_amdgcn_fdot2(ua.p[2], ub.p[2], acc, false);
    acc = __builtin_amdgcn_fdot2(ua.p[3], ub.p[3], acc, false);
#else
    #pragma unroll
    for (int i = 0; i < 8; ++i) acc += (float)a[i] * (float)b[i];
#endif
    return acc;
}

// ---------------- K0a: cast weights (W_hh->f16, W_ih->bf16, W_out->f16 padded)
__global__ __launch_bounds__(256) void cast_kernel(
        const float* __restrict__ whh, const float* __restrict__ wih,
        const float* __restrict__ wout,
        _Float16* __restrict__ whh_h, unsigned short* __restrict__ wih_b,
        _Float16* __restrict__ wout_h) {
    const int nWhh = H_DIM * H_DIM;        // 4194304
    const int nWih = H_DIM * E_DIM;        // 2097152
    const int nWout = 64 * H_DIM;          // 131072 (padded 50->64 rows)
    long long i = (long long)blockIdx.x * 256 + threadIdx.x;
    if (i < nWhh) { whh_h[i] = (_Float16)whh[i]; return; }
    i -= nWhh;
    if (i < nWih) { wih_b[i] = f2bf(wih[i]); return; }
    i -= nWih;
    if (i < nWout) {
        int r = (int)(i >> 11), c = (int)(i & 2047);
        wout_h[i] = (r < T_TAGS) ? (_Float16)wout[r * H_DIM + c] : (_Float16)0.f;
    }
}

// ---------------- K0b: embedding gather -> bf16 X
__global__ __launch_bounds__(256) void embed_kernel(
        const int* __restrict__ sent, const float* __restrict__ emb,
        unsigned short* __restrict__ Xb) {
    size_t i = (size_t)blockIdx.x * 256 + threadIdx.x;   // over S*E
    size_t s = i >> 10, e = i & 1023;
    Xb[i] = f2bf(emb[(size_t)sent[s] * E_DIM + e]);
}

// ---------------- K1: xi = X @ W_ih^T + b_ih + b_hh   (bf16 MFMA, direct-global frags)
__global__ __launch_bounds__(256) void xi_gemm(
        const unsigned short* __restrict__ Xb, const unsigned short* __restrict__ Wb,
        const float* __restrict__ bih, const float* __restrict__ bhh,
        float* __restrict__ xi) {
    int lane = threadIdx.x & 63;
    int w = threadIdx.x >> 6;
    int m0 = blockIdx.y * 64 + w * 16;
    int n0 = blockIdx.x * 16;
    int mi = m0 + (lane & 15);
    int ni = n0 + (lane & 15);
    int q8 = (lane >> 4) * 8;
    const short8* arow = (const short8*)(Xb + (size_t)mi * E_DIM + q8);
    const short8* brow = (const short8*)(Wb + (size_t)ni * E_DIM + q8);
    floatx4 acc = {0.f, 0.f, 0.f, 0.f};
    #pragma unroll 4
    for (int k = 0; k < E_DIM / 32; ++k) {
        short8 a = arow[k * 4];
        short8 b = brow[k * 4];
        acc = __builtin_amdgcn_mfma_f32_16x16x32_bf16(a, b, acc, 0, 0, 0);
    }
    float bias = bih[ni] + bhh[ni];
    int rbase = (lane >> 4) * 4;
    #pragma unroll
    for (int i = 0; i < 4; ++i) {
        xi[(size_t)(m0 + rbase + i) * H_DIM + ni] = acc[i] + bias;
    }
}

// ---------------- K1b: init tagged h ping-pong buffers (runs AFTER xi_gemm: hpk
// aliases the dead tail of X_b). buf0 = (h0, tag 0); buf1 = never-matching tag.
__global__ __launch_bounds__(256) void init_hpk(
        const float* __restrict__ h0, unsigned* __restrict__ hpk) {
    int i = blockIdx.x * 256 + threadIdx.x;   // grid covers H_DIM
    if (i < H_DIM) {
        unsigned short hb = __builtin_bit_cast(unsigned short, (_Float16)h0[i]);
        hpk[i] = (unsigned)hb;            // tag 0 in high 16 bits
        hpk[H_DIM + i] = 0xFFFF0000u;     // tag 0xFFFF never matches (t <= 8191)
    }
}

// ---------------- K2: persistent sequential recurrence, dataflow-synced.
// h element i at step t lives in hpk[(t&1)*H + i] as (tag t)<<16 | f16bits.
// Publish = one relaxed agent-scope 32b store (value+readiness atomic in one
// word). Consumers poll with L2-bypassing loads, caching segments whose tags
// already matched (straggler rounds re-load only missing lines) + s_sleep
// backoff -> poll traffic no longer saturates the IF.
// Ping-pong overwrite safety: tag t+2 can only be written after its producer
// read all tag-t+1 words, whose producers read all tag-t words -> transitively
// every WG consumed tag t before any slot is overwritten.
__global__ __launch_bounds__(256, 1) void rnn_seq(
        const _Float16* __restrict__ Whh, const float* __restrict__ xi,
        unsigned* __restrict__ hpk, _Float16* __restrict__ rnn) {
    __shared__ __align__(16) _Float16 hlds[2][H_DIM];     // 8 KB (double buffer)
    __shared__ float xilds[2][RPW];
    const int tid = threadIdx.x;
    const int wg = blockIdx.x;
    const int rowbase = wg * RPW;
    const int r = tid >> 5;        // 0..7  (row within WG)
    const int j = tid & 31;        // 0..31 (k-slot)

    // W_hh rows live in VGPRs: thread (r,j) holds w[row r][j*8 + c*256 .. +8]
    half8 wreg[8];
    {
        const half8* wrow = (const half8*)(Whh + (size_t)(rowbase + r) * H_DIM);
        #pragma unroll
        for (int c = 0; c < 8; ++c) wreg[c] = wrow[j + c * 32];
    }
    if (tid < RPW) xilds[0][tid] = xi[rowbase + tid];
    __syncthreads();

    for (int t = 0; t < S_LEN; ++t) {
        // xi prefetch for t+1 (drained by first poll's vmcnt(0))
        float xnext = 0.f;
        if (tid < RPW && t + 1 < S_LEN) xnext = xi[(size_t)(t + 1) * H_DIM + rowbase + tid];

        // [A] poll this thread's 8 tagged words of h_t; cache completed halves
        const uint4a* p0 = (const uint4a*)(hpk + (size_t)(t & 1) * H_DIM) + tid * 2;
        const unsigned tg = (unsigned)t;
        uint4a a = {}, b = {};
        bool got0 = false, got1 = false;
        int round = 0;
        for (;;) {
            if (!got0)
                asm volatile("global_load_dwordx4 %0, %1, off sc0 sc1"
                             : "=v"(a) : "v"(p0) : "memory");
            if (!got1)
                asm volatile("global_load_dwordx4 %0, %1, off sc0 sc1"
                             : "=v"(b) : "v"(p0 + 1) : "memory");
            asm volatile("s_waitcnt vmcnt(0)" ::: "memory");
            got0 = got0 | (((a.x >> 16) == tg) & ((a.y >> 16) == tg) &
                           ((a.z >> 16) == tg) & ((a.w >> 16) == tg));
            got1 = got1 | (((b.x >> 16) == tg) & ((b.y >> 16) == tg) &
                           ((b.z >> 16) == tg) & ((b.w >> 16) == tg));
            if (got0 && got1) break;
            if (++round > 1) __builtin_amdgcn_s_sleep(1);
        }

        // strip tags, pack 8 f16 -> 16 B into LDS
        uint4a hp;
        hp.x = (a.x & 0xffffu) | (a.y << 16);
        hp.y = (a.z & 0xffffu) | (a.w << 16);
        hp.z = (b.x & 0xffffu) | (b.y << 16);
        hp.w = (b.z & 0xffffu) | (b.w << 16);
        *(uint4a*)&hlds[t & 1][tid * 8] = hp;
        if (tid < RPW) xilds[(t + 1) & 1][tid] = xnext;
        __syncthreads();

        // [B] partial dot from VGPR weights x LDS h (2-way broadcast reads, free)
        float acc = 0.f;
        const _Float16* hpt = &hlds[t & 1][j * 8];
        #pragma unroll
        for (int c = 0; c < 8; ++c) {
            half8 hv = *(const half8*)(hpt + c * 256);
            acc = dot8(wreg[c], hv, acc);
        }

        // [C] reduce across 32 k-slots
        acc += __shfl_xor(acc, 1);  acc += __shfl_xor(acc, 2);
        acc += __shfl_xor(acc, 4);  acc += __shfl_xor(acc, 8);
        acc += __shfl_xor(acc, 16);

        // [D] h_{t+1} = tanh(xi_t + W_hh h_t); publish tagged word
        if (j == 0) {
            float x = xilds[t & 1][r] + acc;
            float xc = fminf(fmaxf(x, -9.f), 9.f);
            float e = __expf(2.f * xc);                // fast tanh: (e-1)/(e+1)
            float hv = (e - 1.f) / (e + 1.f);
            _Float16 hf = (_Float16)hv;
            unsigned pk = ((unsigned)(t + 1) << 16)
                        | (unsigned)__builtin_bit_cast(unsigned short, hf);
            __hip_atomic_store(&hpk[(size_t)((t + 1) & 1) * H_DIM + rowbase + r], pk,
                               __ATOMIC_RELAXED, __HIP_MEMORY_SCOPE_AGENT);
            rnn[(size_t)t * H_DIM + rowbase + r] = hf;
        }
        // no end barrier: next poll is the sync; hlds double-buffered.
    }
}

// ---------------- K3: head GEMM + log_softmax
__global__ __launch_bounds__(256) void head_kernel(
        const _Float16* __restrict__ rnn, const _Float16* __restrict__ Wout,
        const float* __restrict__ bout, float* __restrict__ out) {
    __shared__ __align__(16) _Float16 h8[8][H_DIM];   // 32 KB
    __shared__ __align__(16) _Float16 wr[H_DIM];      // 4 KB
    __shared__ float tl[8][T_TAGS];
    int tid = threadIdx.x;
    size_t sbase = (size_t)blockIdx.x * 8;
    {
        const uint4* src = (const uint4*)(rnn + sbase * H_DIM);
        uint4* dst = (uint4*)&h8[0][0];
        for (int i = tid; i < 8 * H_DIM / 8; i += 256) dst[i] = src[i];
    }
    __syncthreads();
    int sl = ((tid >> 6) << 1) | ((tid >> 5) & 1);   // 0..7 (2 s per wave)
    int l32 = tid & 31;
    for (int t = 0; t < T_TAGS; ++t) {
        ((uint4*)wr)[tid] = ((const uint4*)(Wout + t * H_DIM))[tid];
        __syncthreads();
        float acc = 0.f;
        const _Float16* hp = &h8[sl][l32 * 64];
        const _Float16* wp = &wr[l32 * 64];
        #pragma unroll
        for (int c = 0; c < 8; ++c)
            acc = dot8(*(const half8*)(hp + c * 8), *(const half8*)(wp + c * 8), acc);
        acc += __shfl_xor(acc, 1);  acc += __shfl_xor(acc, 2);
        acc += __shfl_xor(acc, 4);  acc += __shfl_xor(acc, 8);
        acc += __shfl_xor(acc, 16);
        if (l32 == 0) tl[sl][t] = acc + bout[t];
        __syncthreads();
    }
    if (tid < 8) {
        float m = -1e30f;
        for (int t = 0; t < T_TAGS; ++t) m = fmaxf(m, tl[tid][t]);
        float sum = 0.f;
        for (int t = 0; t < T_TAGS; ++t) sum += expf(tl[tid][t] - m);
        float lse = m + logf(sum);
        for (int t = 0; t < T_TAGS; ++t) out[(sbase + tid) * T_TAGS + t] = tl[tid][t] - lse;
    }
}

extern "C" void kernel_launch(void* const* d_in, const int* in_sizes, int n_in,
                              void* d_out, int out_size, void* d_ws, size_t ws_size,
                              hipStream_t stream) {
    const int*   sent = (const int*)  d_in[0];
    const float* emb  = (const float*)d_in[1];
    const float* wih  = (const float*)d_in[2];
    const float* whh  = (const float*)d_in[3];
    const float* bih  = (const float*)d_in[4];
    const float* bhh  = (const float*)d_in[5];
    const float* wout = (const float*)d_in[6];
    const float* bout = (const float*)d_in[7];
    const float* h0   = (const float*)d_in[8];

    char* ws = (char*)d_ws;
    _Float16*       whh_h  = (_Float16*)      (ws + 0);           //  8 MB
    unsigned short* wih_b  = (unsigned short*)(ws + 8388608);     //  4 MB
    _Float16*       wout_h = (_Float16*)      (ws + 12582912);    //  256 KB
    unsigned short* X_b    = (unsigned short*)(ws + 12845056);    //  16 MB
    unsigned*       hpk    = (unsigned*)      (ws + 29605888);    //  16 KB, aliases X_b tail (dead after xi_gemm)
    float*          xi     = (float*)         (ws + 29622272);    //  64 MB
    _Float16*       rnn    = (_Float16*)      (ws + 96731136);    //  32 MB
    // total footprint ends at 130285568

    {
        const int total = H_DIM * H_DIM + H_DIM * E_DIM + 64 * H_DIM;
        cast_kernel<<<(total + 255) / 256, 256, 0, stream>>>(
            whh, wih, wout, whh_h, wih_b, wout_h);
    }
    embed_kernel<<<(S_LEN * E_DIM) / 256, 256, 0, stream>>>(sent, emb, X_b);
    xi_gemm<<<dim3(H_DIM / 16, S_LEN / 64), 256, 0, stream>>>(X_b, wih_b, bih, bhh, xi);
    init_hpk<<<H_DIM / 256, 256, 0, stream>>>(h0, hpk);
    rnn_seq<<<NWG, 256, 0, stream>>>(whh_h, xi, hpk, rnn);
    head_kernel<<<S_LEN / 8, 256, 0, stream>>>(rnn, wout_h, bout, (float*)d_out);
}

// Round 5
// 26576.047 us; speedup vs baseline: 1.0413x; 1.0413x over previous
//
#include <hip/hip_runtime.h>
#include <hip/hip_bf16.h>

#define S_LEN 8192
#define E_DIM 1024
#define H_DIM 2048
#define T_TAGS 50
#define NWG 256            // persistent workgroups for the recurrence
#define RPW (H_DIM / NWG)  // fallback path: 8 rows per WG

typedef short short8 __attribute__((ext_vector_type(8)));
typedef float floatx4 __attribute__((ext_vector_type(4)));
typedef _Float16 half8 __attribute__((ext_vector_type(8)));
typedef _Float16 half2v __attribute__((ext_vector_type(2)));
typedef unsigned int uint4a __attribute__((ext_vector_type(4)));

__device__ __forceinline__ unsigned short f2bf(float f) {
    unsigned u = __builtin_bit_cast(unsigned, f);
    unsigned r = (u + 0x7fffu + ((u >> 16) & 1u)) >> 16;
    return (unsigned short)r;
}

__device__ __forceinline__ float dot8(half8 a, half8 b, float acc) {
#if __has_builtin(__builtin_amdgcn_fdot2)
    union U { half8 v; half2v p[4]; };
    U ua; ua.v = a; U ub; ub.v = b;
    acc = __builtin_amdgcn_fdot2(ua.p[0], ub.p[0], acc, false);
    acc = __builtin_amdgcn_fdot2(ua.p[1], ub.p[1], acc, false);
    acc = __builtin_amdgcn_fdot2(ua.p[2], ub.p[2], acc, false);
    acc = __builtin_amdgcn_fdot2(ua.p[3], ub.p[3], acc, false);
#else
    #pragma unroll
    for (int i = 0; i < 8; ++i) acc += (float)a[i] * (float)b[i];
#endif
    return acc;
}

__device__ __forceinline__ float fast_tanh(float x) {
    float xc = fminf(fmaxf(x, -9.f), 9.f);
    float e = __expf(2.f * xc);
    return (e - 1.f) / (e + 1.f);
}

// ---------------- K0a: cast weights (W_hh->f16, W_ih->bf16, W_out->f16 padded)
__global__ __launch_bounds__(256) void cast_kernel(
        const float* __restrict__ whh, const float* __restrict__ wih,
        const float* __restrict__ wout,
        _Float16* __restrict__ whh_h, unsigned short* __restrict__ wih_b,
        _Float16* __restrict__ wout_h) {
    const int nWhh = H_DIM * H_DIM;
    const int nWih = H_DIM * E_DIM;
    const int nWout = 64 * H_DIM;
    long long i = (long long)blockIdx.x * 256 + threadIdx.x;
    if (i < nWhh) { whh_h[i] = (_Float16)whh[i]; return; }
    i -= nWhh;
    if (i < nWih) { wih_b[i] = f2bf(wih[i]); return; }
    i -= nWih;
    if (i < nWout) {
        int r = (int)(i >> 11), c = (int)(i & 2047);
        wout_h[i] = (r < T_TAGS) ? (_Float16)wout[r * H_DIM + c] : (_Float16)0.f;
    }
}

// ---------------- K0b: embedding gather -> bf16 X
__global__ __launch_bounds__(256) void embed_kernel(
        const int* __restrict__ sent, const float* __restrict__ emb,
        unsigned short* __restrict__ Xb) {
    size_t i = (size_t)blockIdx.x * 256 + threadIdx.x;
    size_t s = i >> 10, e = i & 1023;
    Xb[i] = f2bf(emb[(size_t)sent[s] * E_DIM + e]);
}

// ---------------- K1: xi = X @ W_ih^T + b_ih + b_hh   (bf16 MFMA)
__global__ __launch_bounds__(256) void xi_gemm(
        const unsigned short* __restrict__ Xb, const unsigned short* __restrict__ Wb,
        const float* __restrict__ bih, const float* __restrict__ bhh,
        float* __restrict__ xi) {
    int lane = threadIdx.x & 63;
    int w = threadIdx.x >> 6;
    int m0 = blockIdx.y * 64 + w * 16;
    int n0 = blockIdx.x * 16;
    int mi = m0 + (lane & 15);
    int ni = n0 + (lane & 15);
    int q8 = (lane >> 4) * 8;
    const short8* arow = (const short8*)(Xb + (size_t)mi * E_DIM + q8);
    const short8* brow = (const short8*)(Wb + (size_t)ni * E_DIM + q8);
    floatx4 acc = {0.f, 0.f, 0.f, 0.f};
    #pragma unroll 4
    for (int k = 0; k < E_DIM / 32; ++k) {
        short8 a = arow[k * 4];
        short8 b = brow[k * 4];
        acc = __builtin_amdgcn_mfma_f32_16x16x32_bf16(a, b, acc, 0, 0, 0);
    }
    float bias = bih[ni] + bhh[ni];
    int rbase = (lane >> 4) * 4;
    #pragma unroll
    for (int i = 0; i < 4; ++i) {
        xi[(size_t)(m0 + rbase + i) * H_DIM + ni] = acc[i] + bias;
    }
}

// ---------------- K1b: init tagged h buffers: global hpk (fallback) + 8 per-XCD
// replicas hx (fast). buf0 = (h0, tag 0); buf1 = never-matching tag.
__global__ __launch_bounds__(256) void init_hpk(
        const float* __restrict__ h0, unsigned* __restrict__ hpk,
        unsigned* __restrict__ hx) {
    int i = blockIdx.x * 256 + threadIdx.x;   // grid covers H_DIM
    if (i < H_DIM) {
        unsigned short hb = __builtin_bit_cast(unsigned short, (_Float16)h0[i]);
        unsigned pk = (unsigned)hb;           // tag 0 in high 16 bits
        hpk[i] = pk;
        hpk[H_DIM + i] = 0xFFFF0000u;
        #pragma unroll
        for (int x = 0; x < 8; ++x) {
            hx[(size_t)x * 2 * H_DIM + i] = pk;
            hx[(size_t)x * 2 * H_DIM + H_DIM + i] = 0xFFFF0000u;
        }
    }
}

// ---------------- K2: persistent sequential recurrence.
// FAST PATH (placement uniform: 32 WGs on every XCD): each XCD runs a full
// independent replica. Publish = __hip_atomic_store(AGENT) [validated r2/r3:
// sc0 sc1 write-through -> updates local L2 en route, reaches IF]. Poll =
// sc0+nt loads (local-L2 scope); after 24 failed rounds escalate to sc0 sc1
// (IF-truth, validated) -> progress guaranteed under ANY L1/L2 staleness,
// since publishes provably reach IF. No unbounded spin exists.
// FALLBACK (placement skew): round-3 global protocol, validated.
__global__ __launch_bounds__(256, 1) void rnn_seq(
        const _Float16* __restrict__ Whh, const float* __restrict__ xi,
        unsigned* __restrict__ hpk, unsigned* __restrict__ hx,
        unsigned* __restrict__ ctl, _Float16* __restrict__ rnn) {
    __shared__ __align__(16) _Float16 hlds[2][H_DIM];     // 8 KB double buffer
    __shared__ float xilds[2][64];
    __shared__ int sh_xcd, sh_rank, sh_fast;
    const int tid = threadIdx.x;
    const int wg = blockIdx.x;

    // ---- one-time election: discover XCD, rank within XCD, uniformity.
    // Bounded: grid=256 at 1 WG/CU on 256 CUs is co-resident (r1-r3 property),
    // and every WG increments ctl[8] exactly once -> the spin terminates.
    if (tid == 0) {
        unsigned x;
        asm volatile("s_getreg_b32 %0, hwreg(HW_REG_XCC_ID)" : "=s"(x));
        x &= 7u;
        unsigned rk = __hip_atomic_fetch_add(&ctl[x], 1u, __ATOMIC_RELAXED,
                                             __HIP_MEMORY_SCOPE_AGENT);
        __hip_atomic_fetch_add(&ctl[8], 1u, __ATOMIC_RELEASE,
                               __HIP_MEMORY_SCOPE_AGENT);
        while (__hip_atomic_load(&ctl[8], __ATOMIC_ACQUIRE,
                                 __HIP_MEMORY_SCOPE_AGENT) < (unsigned)NWG)
            __builtin_amdgcn_s_sleep(2);
        int fast = 1;
        for (int k = 0; k < 8; ++k)
            fast &= (__hip_atomic_load(&ctl[k], __ATOMIC_RELAXED,
                                       __HIP_MEMORY_SCOPE_AGENT) == 32u);
        sh_xcd = (int)x; sh_rank = (int)rk; sh_fast = fast;
    }
    __syncthreads();
    const int xcd = sh_xcd, rank = sh_rank, use_fast = sh_fast;

    if (use_fast && rank < 32) {
        // ================= FAST PATH: per-XCD replica =================
        const int lane = tid & 63;
        const int wv = tid >> 6;           // wave 0..3
        const int wgrow = rank * 64;       // this WG's 64 rows
        unsigned* hxl = hx + (size_t)xcd * 2 * H_DIM;   // local replica buffer

        // weights -> VGPRs: thread(wv,lane) holds rows wgrow+wv*16+i (i<16),
        // cols lane*8 + j*512 .. +8 (j<4). 256 VGPRs of weights.
        half8 w[16][4];
        {
            const _Float16* wb = Whh + (size_t)(wgrow + wv * 16) * H_DIM + lane * 8;
            #pragma unroll
            for (int i = 0; i < 16; ++i) {
                const half8* rp = (const half8*)(wb + (size_t)i * H_DIM);
                #pragma unroll
                for (int j = 0; j < 4; ++j) w[i][j] = rp[j * 64];
            }
        }
        if (tid < 64) xilds[0][tid] = xi[wgrow + tid];
        __syncthreads();

        // bit-reversed row owned by publishing lane (lane<16)
        const int lr = ((lane & 1) << 3) | (((lane >> 1) & 1) << 2) |
                       (((lane >> 2) & 1) << 1) | ((lane >> 3) & 1);

        for (int t = 0; t < S_LEN; ++t) {
            float xnext = 0.f;
            if (tid < 64 && t + 1 < S_LEN)
                xnext = xi[(size_t)(t + 1) * H_DIM + wgrow + tid];

            // [A] poll the 8 tagged words this thread stages. Local scope
            // first; escalate to IF scope if local lines appear stale.
            const uint4a* p = (const uint4a*)(hxl + (size_t)(t & 1) * H_DIM) + tid * 2;
            const unsigned tg = (unsigned)t;
            uint4a a, b;
            int rounds = 0;
            for (;;) {
                if (rounds < 24) {
                    asm volatile(
                        "global_load_dwordx4 %0, %2, off sc0 nt\n\t"
                        "global_load_dwordx4 %1, %3, off sc0 nt\n\t"
                        "s_waitcnt vmcnt(0)"
                        : "=&v"(a), "=&v"(b) : "v"(p), "v"(p + 1) : "memory");
                } else {
                    asm volatile(
                        "global_load_dwordx4 %0, %2, off sc0 sc1\n\t"
                        "global_load_dwordx4 %1, %3, off sc0 sc1\n\t"
                        "s_waitcnt vmcnt(0)"
                        : "=&v"(a), "=&v"(b) : "v"(p), "v"(p + 1) : "memory");
                }
                bool ok = ((a.x >> 16) == tg) & ((a.y >> 16) == tg) &
                          ((a.z >> 16) == tg) & ((a.w >> 16) == tg) &
                          ((b.x >> 16) == tg) & ((b.y >> 16) == tg) &
                          ((b.z >> 16) == tg) & ((b.w >> 16) == tg);
                if (ok) break;
                ++rounds;
                if (rounds > 2) __builtin_amdgcn_s_sleep(1);
            }
            uint4a hp;
            hp.x = (a.x & 0xffffu) | (a.y << 16);
            hp.y = (a.z & 0xffffu) | (a.w << 16);
            hp.z = (b.x & 0xffffu) | (b.y << 16);
            hp.w = (b.z & 0xffffu) | (b.w << 16);
            *(uint4a*)&hlds[t & 1][tid * 8] = hp;
            if (tid < 64) xilds[(t + 1) & 1][tid] = xnext;
            __syncthreads();

            // [B] h slice (shared across this thread's 16 rows): 4x ds_read_b128
            half8 hv[4];
            {
                const half8* hb = (const half8*)&hlds[t & 1][lane * 8];
                #pragma unroll
                for (int j = 0; j < 4; ++j) hv[j] = hb[j * 64];
            }
            float acc[16];
            #pragma unroll
            for (int i = 0; i < 16; ++i) {
                float s = 0.f;
                #pragma unroll
                for (int j = 0; j < 4; ++j) s = dot8(w[i][j], hv[j], s);
                acc[i] = s;
            }

            // [C] register butterfly; after xor 1,2,4,8 lane holds the 16-lane
            // sum of row lr; xor16/32 complete the 64-lane sum.
            {
                bool hi = lane & 1;
                #pragma unroll
                for (int i = 0; i < 8; ++i) {
                    float snd = hi ? acc[i] : acc[i + 8];
                    float kp  = hi ? acc[i + 8] : acc[i];
                    acc[i] = kp + __shfl_xor(snd, 1);
                }
                hi = lane & 2;
                #pragma unroll
                for (int i = 0; i < 4; ++i) {
                    float snd = hi ? acc[i] : acc[i + 4];
                    float kp  = hi ? acc[i + 4] : acc[i];
                    acc[i] = kp + __shfl_xor(snd, 2);
                }
                hi = lane & 4;
                #pragma unroll
                for (int i = 0; i < 2; ++i) {
                    float snd = hi ? acc[i] : acc[i + 2];
                    float kp  = hi ? acc[i + 2] : acc[i];
                    acc[i] = kp + __shfl_xor(snd, 4);
                }
                hi = lane & 8;
                {
                    float snd = hi ? acc[0] : acc[1];
                    float kp  = hi ? acc[1] : acc[0];
                    acc[0] = kp + __shfl_xor(snd, 8);
                }
                acc[0] += __shfl_xor(acc[0], 16);
                acc[0] += __shfl_xor(acc[0], 32);
            }

            // [D] publish h_{t+1} rows (lanes 0..15 of each wave) — validated
            // agent-scope store: updates local L2 en route, reaches IF.
            if (lane < 16) {
                int lrow = wv * 16 + lr;                 // 0..63 within WG
                float hvf = fast_tanh(xilds[t & 1][lrow] + acc[0]);
                _Float16 hf = (_Float16)hvf;
                unsigned pk = ((unsigned)(t + 1) << 16)
                            | (unsigned)__builtin_bit_cast(unsigned short, hf);
                __hip_atomic_store(hxl + (size_t)((t + 1) & 1) * H_DIM + wgrow + lrow,
                                   pk, __ATOMIC_RELAXED, __HIP_MEMORY_SCOPE_AGENT);
                if (xcd == 0)
                    rnn[(size_t)t * H_DIM + wgrow + lrow] = hf;
            }
        }
    } else {
        // ================= FALLBACK: global replica (round-3, validated) =====
        const int rowbase = wg * RPW;
        const int r = tid >> 5;
        const int j = tid & 31;
        half8 wreg[8];
        {
            const half8* wrow = (const half8*)(Whh + (size_t)(rowbase + r) * H_DIM);
            #pragma unroll
            for (int c = 0; c < 8; ++c) wreg[c] = wrow[j + c * 32];
        }
        if (tid < RPW) xilds[0][tid] = xi[rowbase + tid];
        __syncthreads();

        for (int t = 0; t < S_LEN; ++t) {
            float xnext = 0.f;
            if (tid < RPW && t + 1 < S_LEN)
                xnext = xi[(size_t)(t + 1) * H_DIM + rowbase + tid];

            const uint4a* p0 = (const uint4a*)(hpk + (size_t)(t & 1) * H_DIM) + tid * 2;
            const unsigned tg = (unsigned)t;
            uint4a a = {}, b = {};
            bool got0 = false, got1 = false;
            int round = 0;
            for (;;) {
                if (!got0)
                    asm volatile("global_load_dwordx4 %0, %1, off sc0 sc1"
                                 : "=v"(a) : "v"(p0) : "memory");
                if (!got1)
                    asm volatile("global_load_dwordx4 %0, %1, off sc0 sc1"
                                 : "=v"(b) : "v"(p0 + 1) : "memory");
                asm volatile("s_waitcnt vmcnt(0)" ::: "memory");
                got0 = got0 | (((a.x >> 16) == tg) & ((a.y >> 16) == tg) &
                               ((a.z >> 16) == tg) & ((a.w >> 16) == tg));
                got1 = got1 | (((b.x >> 16) == tg) & ((b.y >> 16) == tg) &
                               ((b.z >> 16) == tg) & ((b.w >> 16) == tg));
                if (got0 && got1) break;
                if (++round > 1) __builtin_amdgcn_s_sleep(1);
            }
            uint4a hp;
            hp.x = (a.x & 0xffffu) | (a.y << 16);
            hp.y = (a.z & 0xffffu) | (a.w << 16);
            hp.z = (b.x & 0xffffu) | (b.y << 16);
            hp.w = (b.z & 0xffffu) | (b.w << 16);
            *(uint4a*)&hlds[t & 1][tid * 8] = hp;
            if (tid < RPW) xilds[(t + 1) & 1][tid] = xnext;
            __syncthreads();

            float acc = 0.f;
            const _Float16* hpt = &hlds[t & 1][j * 8];
            #pragma unroll
            for (int c = 0; c < 8; ++c) {
                half8 hvv = *(const half8*)(hpt + c * 256);
                acc = dot8(wreg[c], hvv, acc);
            }
            acc += __shfl_xor(acc, 1);  acc += __shfl_xor(acc, 2);
            acc += __shfl_xor(acc, 4);  acc += __shfl_xor(acc, 8);
            acc += __shfl_xor(acc, 16);

            if (j == 0) {
                float hvf = fast_tanh(xilds[t & 1][r] + acc);
                _Float16 hf = (_Float16)hvf;
                unsigned pk = ((unsigned)(t + 1) << 16)
                            | (unsigned)__builtin_bit_cast(unsigned short, hf);
                __hip_atomic_store(&hpk[(size_t)((t + 1) & 1) * H_DIM + rowbase + r], pk,
                                   __ATOMIC_RELAXED, __HIP_MEMORY_SCOPE_AGENT);
                rnn[(size_t)t * H_DIM + rowbase + r] = hf;
            }
        }
    }
}

// ---------------- K3: head GEMM + log_softmax
__global__ __launch_bounds__(256) void head_kernel(
        const _Float16* __restrict__ rnn, const _Float16* __restrict__ Wout,
        const float* __restrict__ bout, float* __restrict__ out) {
    __shared__ __align__(16) _Float16 h8[8][H_DIM];
    __shared__ __align__(16) _Float16 wr[H_DIM];
    __shared__ float tl[8][T_TAGS];
    int tid = threadIdx.x;
    size_t sbase = (size_t)blockIdx.x * 8;
    {
        const uint4* src = (const uint4*)(rnn + sbase * H_DIM);
        uint4* dst = (uint4*)&h8[0][0];
        for (int i = tid; i < 8 * H_DIM / 8; i += 256) dst[i] = src[i];
    }
    __syncthreads();
    int sl = ((tid >> 6) << 1) | ((tid >> 5) & 1);
    int l32 = tid & 31;
    for (int t = 0; t < T_TAGS; ++t) {
        ((uint4*)wr)[tid] = ((const uint4*)(Wout + t * H_DIM))[tid];
        __syncthreads();
        float acc = 0.f;
        const _Float16* hp = &h8[sl][l32 * 64];
        const _Float16* wp = &wr[l32 * 64];
        #pragma unroll
        for (int c = 0; c < 8; ++c)
            acc = dot8(*(const half8*)(hp + c * 8), *(const half8*)(wp + c * 8), acc);
        acc += __shfl_xor(acc, 1);  acc += __shfl_xor(acc, 2);
        acc += __shfl_xor(acc, 4);  acc += __shfl_xor(acc, 8);
        acc += __shfl_xor(acc, 16);
        if (l32 == 0) tl[sl][t] = acc + bout[t];
        __syncthreads();
    }
    if (tid < 8) {
        float m = -1e30f;
        for (int t = 0; t < T_TAGS; ++t) m = fmaxf(m, tl[tid][t]);
        float sum = 0.f;
        for (int t = 0; t < T_TAGS; ++t) sum += expf(tl[tid][t] - m);
        float lse = m + logf(sum);
        for (int t = 0; t < T_TAGS; ++t) out[(sbase + tid) * T_TAGS + t] = tl[tid][t] - lse;
    }
}

extern "C" void kernel_launch(void* const* d_in, const int* in_sizes, int n_in,
                              void* d_out, int out_size, void* d_ws, size_t ws_size,
                              hipStream_t stream) {
    const int*   sent = (const int*)  d_in[0];
    const float* emb  = (const float*)d_in[1];
    const float* wih  = (const float*)d_in[2];
    const float* whh  = (const float*)d_in[3];
    const float* bih  = (const float*)d_in[4];
    const float* bhh  = (const float*)d_in[5];
    const float* wout = (const float*)d_in[6];
    const float* bout = (const float*)d_in[7];
    const float* h0   = (const float*)d_in[8];

    char* ws = (char*)d_ws;
    _Float16*       whh_h  = (_Float16*)      (ws + 0);           //  8 MB
    unsigned short* wih_b  = (unsigned short*)(ws + 8388608);     //  4 MB
    _Float16*       wout_h = (_Float16*)      (ws + 12582912);    //  256 KB
    unsigned short* X_b    = (unsigned short*)(ws + 12845056);    //  16 MB
    unsigned*       hx     = (unsigned*)      (ws + 13000704);    //  128 KB, aliases X_b (dead after xi_gemm)
    unsigned*       hpk    = (unsigned*)      (ws + 29605888);    //  16 KB, aliases X_b tail
    float*          xi     = (float*)         (ws + 29622272);    //  64 MB
    _Float16*       rnn    = (_Float16*)      (ws + 96731136);    //  32 MB
    unsigned*       ctl    = (unsigned*)      (ws + 130285568);   //  64 B election counters

    hipMemsetAsync(ctl, 0, 64, stream);
    {
        const int total = H_DIM * H_DIM + H_DIM * E_DIM + 64 * H_DIM;
        cast_kernel<<<(total + 255) / 256, 256, 0, stream>>>(
            whh, wih, wout, whh_h, wih_b, wout_h);
    }
    embed_kernel<<<(S_LEN * E_DIM) / 256, 256, 0, stream>>>(sent, emb, X_b);
    xi_gemm<<<dim3(H_DIM / 16, S_LEN / 64), 256, 0, stream>>>(X_b, wih_b, bih, bhh, xi);
    init_hpk<<<H_DIM / 256, 256, 0, stream>>>(h0, hpk, hx);
    rnn_seq<<<NWG, 256, 0, stream>>>(whh_h, xi, hpk, hx, ctl, rnn);
    head_kernel<<<S_LEN / 8, 256, 0, stream>>>(rnn, wout_h, bout, (float*)d_out);
}